// Round 7
// baseline (508.668 us; speedup 1.0000x reference)
//
#include <hip/hip_runtime.h>

// Node2Edge2Node GNN block, MI355X (gfx950) — R10: k_fill LDS-direct rank.
//
//   agg[v] = (Σ_{e->v} x[src_e]) @ W1a  +  cnt_v * (x[v] @ W1b)
//          + (Σ_{e->v} ea_e)    @ W1c  +  cnt_v * b1
//   out    = [agg | x] @ W2 + b2
//
// Budget: ~400us/iter harness poison fills (fixed, 82% HBM peak) + ~109us
// controllable. R10 banks the last verified lever: k_fill loads its
// PREFIXED histogram column (colscan output) into LDS and uses a single
// lds_fetch_add as combined cross-block offset + intra-block rank — kills
// the per-edge random hb[d] global gather and the rk zeroing pass (scheme
// correctness-proven in R8's P3). Everything else identical to R9.
// Pipeline: k_prep_hist -> k_colscan -> k_fill -> k_sum -> k_out.

#define NN 10000
#define ED 640000
#define D  128
#define NB 64                 // histogram blocks
#define EPB (ED / NB)         // 10000 edges per block (exact)
#define ST 192                // CSR slots per node (Poisson(64): P(>192)~1e-30)

typedef __bf16 bf16;
typedef bf16  bf16x8 __attribute__((ext_vector_type(8)));
typedef float f32x4  __attribute__((ext_vector_type(4)));

__device__ __forceinline__ bf16 f2b(float f) {
  unsigned u = __builtin_bit_cast(unsigned, f);
  u += 0x7fffu + ((u >> 16) & 1u);               // RTNE
  unsigned short h = (unsigned short)(u >> 16);
  return __builtin_bit_cast(bf16, h);
}

__device__ __forceinline__ bf16x8 bzero8() {
  bf16 z = __builtin_bit_cast(bf16, (unsigned short)0);
  bf16x8 v = {z, z, z, z, z, z, z, z};
  return v;
}

// ---------------------------------------------------------------------------
// K1: blocks 0..63: per-chunk LDS histogram of dst (LDS atomics, int4 I/O).
//     blocks 64..: x -> bf16; pack W1 (384x128), W2 (256x128) into MFMA
//     B-frag layout: Bp[((kb*8+t)*64+L)*8+j] = W[kb*32+(L>>4)*8+j][t*16+(L&15)]
// ---------------------------------------------------------------------------
__global__ __launch_bounds__(256) void k_prep_hist(const float* __restrict__ x,
                                                   const float* __restrict__ W1,
                                                   const float* __restrict__ W2,
                                                   const int*   __restrict__ dst,
                                                   bf16* __restrict__ xb,
                                                   bf16* __restrict__ W1p,
                                                   bf16* __restrict__ W2p,
                                                   int*  __restrict__ hist) {
  __shared__ __align__(16) int h[NN];
  int tid = threadIdx.x;
  if (blockIdx.x < NB) {                // ---- histogram part
    int b = blockIdx.x;
    int4 z4 = make_int4(0, 0, 0, 0);
    for (int i = tid; i < NN / 4; i += 256) ((int4*)h)[i] = z4;
    __syncthreads();
    const int4* d4 = (const int4*)(dst + b * EPB);
    for (int i = tid; i < EPB / 4; i += 256) {
      int4 dd = d4[i];
      atomicAdd(&h[dd.x], 1);
      atomicAdd(&h[dd.y], 1);
      atomicAdd(&h[dd.z], 1);
      atomicAdd(&h[dd.w], 1);
    }
    __syncthreads();
    int4* outp = (int4*)(hist + (size_t)b * NN);
    for (int i = tid; i < NN / 4; i += 256) outp[i] = ((const int4*)h)[i];
    return;
  }
  // ---- prep part
  int id = (blockIdx.x - NB) * 256 + tid;
  if (id < 160000) {                    // xb: 10000*128/8 chunks
    int i = id * 8;
    f32x4 a = *(const f32x4*)(x + i);
    f32x4 b = *(const f32x4*)(x + i + 4);
    bf16x8 hh;
    hh[0]=f2b(a[0]); hh[1]=f2b(a[1]); hh[2]=f2b(a[2]); hh[3]=f2b(a[3]);
    hh[4]=f2b(b[0]); hh[5]=f2b(b[1]); hh[6]=f2b(b[2]); hh[7]=f2b(b[3]);
    *(bf16x8*)(xb + i) = hh;
  } else if (id < 166144) {             // W1p: kb 0..11 (K=384)
    int o8 = id - 160000;
    int kb = o8 >> 9, rem = o8 & 511, t = rem >> 6, L = rem & 63;
    int col  = t * 16 + (L & 15);
    int row0 = kb * 32 + (L >> 4) * 8;
    bf16x8 hh;
    #pragma unroll
    for (int j = 0; j < 8; j++) hh[j] = f2b(W1[(row0 + j) * D + col]);
    *(bf16x8*)(W1p + o8 * 8) = hh;
  } else if (id < 170240) {             // W2p: kb 0..7 (K=256)
    int o8 = id - 166144;
    int kb = o8 >> 9, rem = o8 & 511, t = rem >> 6, L = rem & 63;
    int col  = t * 16 + (L & 15);
    int row0 = kb * 32 + (L >> 4) * 8;
    bf16x8 hh;
    #pragma unroll
    for (int j = 0; j < 8; j++) hh[j] = f2b(W2[(row0 + j) * D + col]);
    *(bf16x8*)(W2p + o8 * 8) = hh;
  }
}

// ---------------------------------------------------------------------------
// K2: per-node exclusive prefix over the NB block-partials (in place),
// total into counts. Coalesced across v.
// ---------------------------------------------------------------------------
__global__ __launch_bounds__(256) void k_colscan(int* __restrict__ hist,
                                                 int* __restrict__ counts) {
  int v = blockIdx.x * 256 + threadIdx.x;
  if (v >= NN) return;
  int run = 0;
  #pragma unroll
  for (int b = 0; b < NB; b++) {
    int t = hist[b * NN + v];
    hist[b * NN + v] = run;
    run += t;
  }
  counts[v] = run;
}

// ---------------------------------------------------------------------------
// K3: scatter edges into slotted CSR. Block b loads its PREFIXED histogram
// column into LDS; pos = d*ST + lds_fetch_add(h[d]) — the LDS counter serves
// as cross-block offset + intra-block rank combined (R8-P3 scheme). Slots
// for block b are [prefix_b[d], prefix_{b+1}[d]) — bijective per node.
// ---------------------------------------------------------------------------
__global__ __launch_bounds__(256) void k_fill(const int* __restrict__ src,
                                              const int* __restrict__ dst,
                                              const int* __restrict__ hist,
                                              int2* __restrict__ csr) {
  __shared__ __align__(16) int h[NN];
  int b = blockIdx.x, tid = threadIdx.x;
  const int4* hp = (const int4*)(hist + (size_t)b * NN);
  for (int i = tid; i < NN / 4; i += 256) ((int4*)h)[i] = hp[i];
  __syncthreads();
  int base = b * EPB;
  const int4* d4 = (const int4*)(dst + base);
  const int4* s4 = (const int4*)(src + base);
  for (int i = tid; i < EPB / 4; i += 256) {
    int4 dd = d4[i];
    int4 ss = s4[i];
    int e = base + i * 4;
    {
      int r = atomicAdd(&h[dd.x], 1);
      csr[(size_t)dd.x * ST + r] = make_int2(e + 0, ss.x);
    }
    {
      int r = atomicAdd(&h[dd.y], 1);
      csr[(size_t)dd.y * ST + r] = make_int2(e + 1, ss.y);
    }
    {
      int r = atomicAdd(&h[dd.z], 1);
      csr[(size_t)dd.z * ST + r] = make_int2(e + 2, ss.z);
    }
    {
      int r = atomicAdd(&h[dd.w], 1);
      csr[(size_t)dd.w * ST + r] = make_int2(e + 3, ss.w);
    }
  }
}

// ---------------------------------------------------------------------------
// K4: per-node segment sums -> bf16 A1 row [sx | cnt*x | sea] (GEMM-ready).
// One wave per node (10000 waves: max TLP for the 327MB ea stream).
// Lane = g*16+l: group g handles edges g, g+4, ...; lane covers cols
// [8l,8l+8). ea/csr loads NON-TEMPORAL (read-once; keep xb L2-resident).
// After the xor-reduce every lane holds the full sums; sections 0/1/2 of the
// wave store sx / sea / cnt*x (f2b applied here — same point as before).
// ---------------------------------------------------------------------------
__global__ __launch_bounds__(256) void k_sum(const bf16*  __restrict__ xb,
                                             const float* __restrict__ ea,
                                             const int*   __restrict__ counts,
                                             const int2*  __restrict__ csr,
                                             bf16* __restrict__ a1) {
  int gwave = (blockIdx.x * 256 + threadIdx.x) >> 6;   // 0..9999
  if (gwave >= NN) return;
  int lane = threadIdx.x & 63;
  int g = lane >> 4, l = lane & 15;
  int cnt = counts[gwave];
  const int2* cbase = csr + (size_t)gwave * ST;

  f32x4 ax0 = {0.f,0.f,0.f,0.f}, ax1 = {0.f,0.f,0.f,0.f};
  f32x4 ae0 = {0.f,0.f,0.f,0.f}, ae1 = {0.f,0.f,0.f,0.f};

  #pragma unroll 2
  for (int e = g; e < cnt; e += 4) {
    long long cp = __builtin_nontemporal_load((const long long*)(cbase + e));
    int2 es = __builtin_bit_cast(int2, cp);
    const f32x4* ep = (const f32x4*)(ea + (size_t)es.x * D + l * 8);
    f32x4 f0 = __builtin_nontemporal_load(ep);
    f32x4 f1 = __builtin_nontemporal_load(ep + 1);
    bf16x8 hx = *(const bf16x8*)(xb + (size_t)es.y * D + l * 8);
    ax0[0] += (float)hx[0]; ax0[1] += (float)hx[1];
    ax0[2] += (float)hx[2]; ax0[3] += (float)hx[3];
    ax1[0] += (float)hx[4]; ax1[1] += (float)hx[5];
    ax1[2] += (float)hx[6]; ax1[3] += (float)hx[7];
    ae0 += f0;
    ae1 += f1;
  }
  // reduce across the 4 groups (lane bits 4,5) — all lanes end with totals
  #pragma unroll
  for (int i = 0; i < 4; i++) {
    ax0[i] += __shfl_xor(ax0[i], 16, 64); ax0[i] += __shfl_xor(ax0[i], 32, 64);
    ax1[i] += __shfl_xor(ax1[i], 16, 64); ax1[i] += __shfl_xor(ax1[i], 32, 64);
    ae0[i] += __shfl_xor(ae0[i], 16, 64); ae0[i] += __shfl_xor(ae0[i], 32, 64);
    ae1[i] += __shfl_xor(ae1[i], 16, 64); ae1[i] += __shfl_xor(ae1[i], 32, 64);
  }
  bf16* base = a1 + (size_t)gwave * 384;
  if (g == 0) {                         // sx -> cols [0,128)
    bf16x8 h;
    h[0]=f2b(ax0[0]); h[1]=f2b(ax0[1]); h[2]=f2b(ax0[2]); h[3]=f2b(ax0[3]);
    h[4]=f2b(ax1[0]); h[5]=f2b(ax1[1]); h[6]=f2b(ax1[2]); h[7]=f2b(ax1[3]);
    __builtin_nontemporal_store(h, (bf16x8*)(base + l * 8));
  } else if (g == 1) {                  // sea -> cols [256,384)
    bf16x8 h;
    h[0]=f2b(ae0[0]); h[1]=f2b(ae0[1]); h[2]=f2b(ae0[2]); h[3]=f2b(ae0[3]);
    h[4]=f2b(ae1[0]); h[5]=f2b(ae1[1]); h[6]=f2b(ae1[2]); h[7]=f2b(ae1[3]);
    __builtin_nontemporal_store(h, (bf16x8*)(base + 256 + l * 8));
  } else if (g == 2) {                  // cnt*x -> cols [128,256)
    float cntf = (float)cnt;
    bf16x8 hx = *(const bf16x8*)(xb + (size_t)gwave * D + l * 8);
    bf16x8 h;
    #pragma unroll
    for (int k = 0; k < 8; k++) h[k] = f2b((float)hx[k] * cntf);
    __builtin_nontemporal_store(h, (bf16x8*)(base + 128 + l * 8));
  }
}

// ---------------------------------------------------------------------------
// K5: fused per-node GEMMs.  64 nodes/block, 157 blocks.
//   stage1: agg = A1[64x384] @ W1 + cnt*b1          (K=384, A1 precomputed)
//   stage2: out = [bf16(agg) | xb] @ W2 + b2        (K=256)
// One LDS buffer reused: A1 stride 392 bf16, A2 stride 264 bf16.
// ---------------------------------------------------------------------------
__global__ __launch_bounds__(256) void k_out(const bf16*  __restrict__ a1,
                                             const bf16*  __restrict__ xb,
                                             const bf16*  __restrict__ W1p,
                                             const bf16*  __restrict__ W2p,
                                             const float* __restrict__ b1,
                                             const float* __restrict__ b2,
                                             const int*   __restrict__ counts,
                                             float* __restrict__ out) {
  __shared__ __align__(16) bf16 lds[64 * 392];   // 50.2 KB
  int tid  = threadIdx.x;
  int wave = tid >> 6, lane = tid & 63, quad = lane >> 4, l16 = lane & 15;
  int n0 = blockIdx.x * 64;

  // ---- stage-1 staging: pure row copy of precomputed A1 (nt: read-once)
  #pragma unroll
  for (int i = 0; i < 4; i++) {
    int m = (tid >> 4) + 16 * i;
    int v = n0 + m;
    int cl = tid & 15;
    #pragma unroll
    for (int j = 0; j < 3; j++) {
      int c = cl + 16 * j;              // chunk 0..47
      bf16x8 h = bzero8();
      if (v < NN)
        h = __builtin_nontemporal_load((const bf16x8*)(a1 + (size_t)v * 384 + c * 8));
      *(bf16x8*)&lds[m * 392 + c * 8] = h;
    }
  }
  __syncthreads();

  // ---- stage-1 GEMM (K=384)
  f32x4 acc[4][2];
  #pragma unroll
  for (int mt = 0; mt < 4; mt++)
    #pragma unroll
    for (int tt = 0; tt < 2; tt++) acc[mt][tt] = (f32x4){0.f, 0.f, 0.f, 0.f};

  #pragma unroll
  for (int kb = 0; kb < 12; kb++) {
    bf16x8 B0 = *(const bf16x8*)(W1p + ((kb * 8 + wave * 2 + 0) * 64 + lane) * 8);
    bf16x8 B1 = *(const bf16x8*)(W1p + ((kb * 8 + wave * 2 + 1) * 64 + lane) * 8);
    #pragma unroll
    for (int mt = 0; mt < 4; mt++) {
      bf16x8 a = *(const bf16x8*)&lds[(mt * 16 + l16) * 392 + kb * 32 + quad * 8];
      acc[mt][0] = __builtin_amdgcn_mfma_f32_16x16x32_bf16(a, B0, acc[mt][0], 0, 0, 0);
      acc[mt][1] = __builtin_amdgcn_mfma_f32_16x16x32_bf16(a, B1, acc[mt][1], 0, 0, 0);
    }
  }
  __syncthreads();                      // all A1 reads done; lds reused as A2

  // ---- epilogue-1: agg = acc + cnt*b1 -> bf16 into A2 cols [0,128), stride 264
  #pragma unroll
  for (int tt = 0; tt < 2; tt++) {
    int col = wave * 32 + tt * 16 + l16;
    float bb = b1[col];
    #pragma unroll
    for (int mt = 0; mt < 4; mt++)
      #pragma unroll
      for (int r = 0; r < 4; r++) {
        int m = mt * 16 + quad * 4 + r;
        int v = n0 + m;
        float cntf = (v < NN) ? (float)counts[v] : 0.f;
        lds[m * 264 + col] = f2b(acc[mt][tt][r] + cntf * bb);
      }
  }
  // ---- A2 cols [128,256) = xb
  #pragma unroll
  for (int i = 0; i < 4; i++) {
    int m = (tid >> 4) + 16 * i;
    int c = tid & 15;
    int v = n0 + m;
    bf16x8 h = (v < NN) ? *(const bf16x8*)(xb + (size_t)v * D + c * 8) : bzero8();
    *(bf16x8*)&lds[m * 264 + 128 + c * 8] = h;
  }
  __syncthreads();

  // ---- stage-2 GEMM (K=256)
  f32x4 acc2[4][2];
  #pragma unroll
  for (int mt = 0; mt < 4; mt++)
    #pragma unroll
    for (int tt = 0; tt < 2; tt++) acc2[mt][tt] = (f32x4){0.f, 0.f, 0.f, 0.f};

  #pragma unroll
  for (int kb = 0; kb < 8; kb++) {
    bf16x8 B0 = *(const bf16x8*)(W2p + ((kb * 8 + wave * 2 + 0) * 64 + lane) * 8);
    bf16x8 B1 = *(const bf16x8*)(W2p + ((kb * 8 + wave * 2 + 1) * 64 + lane) * 8);
    #pragma unroll
    for (int mt = 0; mt < 4; mt++) {
      bf16x8 a = *(const bf16x8*)&lds[(mt * 16 + l16) * 264 + kb * 32 + quad * 8];
      acc2[mt][0] = __builtin_amdgcn_mfma_f32_16x16x32_bf16(a, B0, acc2[mt][0], 0, 0, 0);
      acc2[mt][1] = __builtin_amdgcn_mfma_f32_16x16x32_bf16(a, B1, acc2[mt][1], 0, 0, 0);
    }
  }

  #pragma unroll
  for (int tt = 0; tt < 2; tt++) {
    int col = wave * 32 + tt * 16 + l16;
    float bb = b2[col];
    #pragma unroll
    for (int mt = 0; mt < 4; mt++)
      #pragma unroll
      for (int r = 0; r < 4; r++) {
        int v = n0 + mt * 16 + quad * 4 + r;
        if (v < NN) out[(size_t)v * D + col] = acc2[mt][tt][r] + bb;
      }
  }
}

// ---------------------------------------------------------------------------
extern "C" void kernel_launch(void* const* d_in, const int* in_sizes, int n_in,
                              void* d_out, int out_size, void* d_ws, size_t ws_size,
                              hipStream_t stream) {
  const float* x  = (const float*)d_in[0];
  const int*   ei = (const int*)  d_in[1];   // [2, E]: src = ei, dst = ei + ED
  const float* ea = (const float*)d_in[2];
  const float* W1 = (const float*)d_in[3];
  const float* b1 = (const float*)d_in[4];
  const float* W2 = (const float*)d_in[5];
  const float* b2 = (const float*)d_in[6];
  float* out = (float*)d_out;

  char* ws = (char*)d_ws;
  size_t off = 0;
  auto alloc = [&](size_t bytes) -> void* {
    void* p = ws + off;
    off += (bytes + 255) & ~(size_t)255;
    return p;
  };
  bf16*  xb      = (bf16*)alloc((size_t)NN * D * 2);
  bf16*  W1p     = (bf16*)alloc(49152 * 2);       // 384*128
  bf16*  W2p     = (bf16*)alloc(32768 * 2);       // 256*128
  bf16*  a1      = (bf16*)alloc((size_t)NN * 384 * 2);  // 7.68 MB GEMM operand
  int*   counts  = (int*)alloc(NN * 4);
  int*   hist    = (int*)alloc((size_t)NB * NN * 4);    // 2.56 MB block-partials
  int2*  csr     = (int2*)alloc((size_t)NN * ST * 8);   // 15.4 MB slotted CSR
  (void)ws_size; (void)in_sizes; (void)n_in; (void)out_size;  // ~29 MB

  const int* src = ei;
  const int* dst = ei + ED;

  k_prep_hist<<<NB + 665, 256, 0, stream>>>(x, W1, W2, dst, xb, W1p, W2p, hist);
  k_colscan<<<40, 256, 0, stream>>>(hist, counts);
  k_fill<<<NB, 256, 0, stream>>>(src, dst, hist, csr);
  k_sum<<<2500, 256, 0, stream>>>(xb, ea, counts, csr, a1);
  k_out<<<157, 256, 0, stream>>>(a1, xb, W1p, W2p, b1, b2, counts, out);
}